// Round 1
// baseline (2243.426 us; speedup 1.0000x reference)
//
#include <hip/hip_runtime.h>
#include <hip/hip_bf16.h>
#include <math.h>

#define T_SEQ 2048
#define E_DIM 1024
#define HD    32      // head_dim for q/k sub-heads
#define NH    16      // H (v heads, dim 64)
#define QB    32      // query rows per block (attention)
#define KB    64      // key rows per tile (attention)

__device__ __forceinline__ float4 ldg4(const float* p) {
    return *reinterpret_cast<const float4*>(p);
}

// ---------------------------------------------------------------------------
// C[M,N] = A[M,K] @ W[N,K]^T   (torch Linear), fp32, 64x64 tile, BK=16
// ---------------------------------------------------------------------------
__device__ __forceinline__ void gemm_body(const float* __restrict__ A,
                                          const float* __restrict__ W,
                                          float* __restrict__ C,
                                          int M, int N, int K)
{
    __shared__ float As[16][68];   // [k][m], pad 68 keeps float4 alignment
    __shared__ float Bs[16][68];   // [k][n]

    const int tid = threadIdx.x;
    const int tx = tid & 15, ty = tid >> 4;
    const int m0 = blockIdx.y * 64, n0 = blockIdx.x * 64;

    float acc[4][4] = {};

    const int lrow = tid >> 2;            // 0..63
    const int lc4  = (tid & 3) * 4;       // 0,4,8,12
    const float* Ag = A + (size_t)(m0 + lrow) * K + lc4;
    const float* Wg = W + (size_t)(n0 + lrow) * K + lc4;

    for (int k0 = 0; k0 < K; k0 += 16) {
        float4 a = ldg4(Ag + k0);
        float4 b = ldg4(Wg + k0);
        __syncthreads();   // previous compute done before overwrite
        As[lc4 + 0][lrow] = a.x; As[lc4 + 1][lrow] = a.y;
        As[lc4 + 2][lrow] = a.z; As[lc4 + 3][lrow] = a.w;
        Bs[lc4 + 0][lrow] = b.x; Bs[lc4 + 1][lrow] = b.y;
        Bs[lc4 + 2][lrow] = b.z; Bs[lc4 + 3][lrow] = b.w;
        __syncthreads();
#pragma unroll
        for (int kk = 0; kk < 16; kk++) {
            const float4 av = *reinterpret_cast<const float4*>(&As[kk][ty * 4]);
            const float4 bv = *reinterpret_cast<const float4*>(&Bs[kk][tx * 4]);
            const float a4[4] = {av.x, av.y, av.z, av.w};
            const float b4[4] = {bv.x, bv.y, bv.z, bv.w};
#pragma unroll
            for (int i = 0; i < 4; i++)
#pragma unroll
                for (int j = 0; j < 4; j++)
                    acc[i][j] = fmaf(a4[i], b4[j], acc[i][j]);
        }
    }

#pragma unroll
    for (int i = 0; i < 4; i++) {
        float4 o;
        o.x = acc[i][0]; o.y = acc[i][1]; o.z = acc[i][2]; o.w = acc[i][3];
        *reinterpret_cast<float4*>(&C[(size_t)(m0 + ty * 4 + i) * N + n0 + tx * 4]) = o;
    }
}

__global__ __launch_bounds__(256)
void gemm_qkv(const float* __restrict__ A,
              const float* __restrict__ W0, const float* __restrict__ W1,
              const float* __restrict__ W2,
              float* __restrict__ C0, float* __restrict__ C1, float* __restrict__ C2,
              int M, int N, int K)
{
    const float* W = (blockIdx.z == 0) ? W0 : (blockIdx.z == 1) ? W1 : W2;
    float*       C = (blockIdx.z == 0) ? C0 : (blockIdx.z == 1) ? C1 : C2;
    gemm_body(A, W, C, M, N, K);
}

__global__ __launch_bounds__(256)
void gemm_one(const float* __restrict__ A, const float* __restrict__ W,
              float* __restrict__ C, int M, int N, int K)
{
    gemm_body(A, W, C, M, N, K);
}

// ---------------------------------------------------------------------------
// Differential attention, flash-style dual softmax + fused RMSNorm epilogue.
// Grid: (T/QB, NH). Block: 256 threads.
// Writes normed[t, h*64 + d]  (the already-transposed [T, E] layout).
// ---------------------------------------------------------------------------
__global__ __launch_bounds__(256)
void diff_attn(const float* __restrict__ Q, const float* __restrict__ Km,
               const float* __restrict__ V, float* __restrict__ normed,
               const float* __restrict__ lq1, const float* __restrict__ lk1,
               const float* __restrict__ lq2, const float* __restrict__ lk2,
               const float* __restrict__ gamma)
{
    __shared__ float q1s[QB][36], q2s[QB][36];   // [row][hd], pad 36 (16B-aligned rows)
    __shared__ float k1s[KB][36], k2s[KB][36];
    __shared__ float vs[KB][68];                 // [key][64], pad 68
    __shared__ float S1s[QB][65], S2s[QB][65];   // pad 65: bank-clean scalar access
    __shared__ float m1s[QB], l1s[QB], c1s[QB];
    __shared__ float m2s[QB], l2s[QB], c2s[QB];
    __shared__ float red[8][QB];

    const int tid = threadIdx.x;
    const int qb  = blockIdx.x;          // 0..63
    const int h   = blockIdx.y;          // 0..15
    const int q0  = qb * QB;
    const int off1 = (2 * h) * HD;
    const int off2 = off1 + HD;
    const int offv = h * (2 * HD);

    // lambda_full (computed redundantly; trivially cheap, L1-cached loads)
    float s1 = 0.f, s2 = 0.f;
#pragma unroll
    for (int i = 0; i < HD; i++) {
        s1 += lq1[i] * lk1[i];
        s2 += lq2[i] * lk2[i];
    }
    const float LI = 0.4707130183435841f;           // 0.8 - 0.6*exp(-0.6)
    const float lambda_full = expf(s1) - expf(s2) + LI;
    const float scaling = 0.17677669529663687f;     // 32^-0.5

    // load q tiles: QB x 32 = 256 float4 per matrix
    {
        const int row = tid >> 3, c4 = (tid & 7) * 4;
        float4 a = ldg4(&Q[(size_t)(q0 + row) * E_DIM + off1 + c4]);
        q1s[row][c4 + 0] = a.x; q1s[row][c4 + 1] = a.y;
        q1s[row][c4 + 2] = a.z; q1s[row][c4 + 3] = a.w;
        float4 b = ldg4(&Q[(size_t)(q0 + row) * E_DIM + off2 + c4]);
        q2s[row][c4 + 0] = b.x; q2s[row][c4 + 1] = b.y;
        q2s[row][c4 + 2] = b.z; q2s[row][c4 + 3] = b.w;
    }
    if (tid < QB) {
        m1s[tid] = -INFINITY; l1s[tid] = 0.f;
        m2s[tid] = -INFINITY; l2s[tid] = 0.f;
    }

    float acc1[8] = {}, acc2[8] = {};
    const int r_pv = tid & 31;
    const int dg   = tid >> 5;       // 0..7
    const int d0   = dg * 8;

    const int nkb = ((q0 + QB - 1) >> 6) + 1;   // causal: tiles 0..nkb-1

    for (int kb = 0; kb < nkb; kb++) {
        const int j0 = kb * KB;
        __syncthreads();   // prev PV / init done before overwriting k,v tiles

        // load k1,k2 tiles: KB x 32 = 512 float4 each
#pragma unroll
        for (int p = 0; p < 2; p++) {
            const int f = tid + p * 256;
            const int row = f >> 3, c4 = (f & 7) * 4;
            float4 a = ldg4(&Km[(size_t)(j0 + row) * E_DIM + off1 + c4]);
            k1s[row][c4 + 0] = a.x; k1s[row][c4 + 1] = a.y;
            k1s[row][c4 + 2] = a.z; k1s[row][c4 + 3] = a.w;
            float4 b = ldg4(&Km[(size_t)(j0 + row) * E_DIM + off2 + c4]);
            k2s[row][c4 + 0] = b.x; k2s[row][c4 + 1] = b.y;
            k2s[row][c4 + 2] = b.z; k2s[row][c4 + 3] = b.w;
        }
        // load v tile: KB x 64 = 1024 float4
#pragma unroll
        for (int p = 0; p < 4; p++) {
            const int f = tid + p * 256;
            const int row = f >> 4, c4 = (f & 15) * 4;
            float4 a = ldg4(&V[(size_t)(j0 + row) * E_DIM + offv + c4]);
            vs[row][c4 + 0] = a.x; vs[row][c4 + 1] = a.y;
            vs[row][c4 + 2] = a.z; vs[row][c4 + 3] = a.w;
        }
        __syncthreads();

        // scores: each thread 8 (r,j) pairs, both sub-heads
#pragma unroll
        for (int s = 0; s < 8; s++) {
            const int e = tid + s * 256;
            const int r = e >> 6, j = e & 63;
            float d1 = 0.f, d2 = 0.f;
#pragma unroll
            for (int i4 = 0; i4 < 8; i4++) {
                const float4 qa = *reinterpret_cast<const float4*>(&q1s[r][i4 * 4]);
                const float4 ka = *reinterpret_cast<const float4*>(&k1s[j][i4 * 4]);
                const float4 qb2 = *reinterpret_cast<const float4*>(&q2s[r][i4 * 4]);
                const float4 kb2 = *reinterpret_cast<const float4*>(&k2s[j][i4 * 4]);
                d1 += qa.x * ka.x + qa.y * ka.y + qa.z * ka.z + qa.w * ka.w;
                d2 += qb2.x * kb2.x + qb2.y * kb2.y + qb2.z * kb2.z + qb2.w * kb2.w;
            }
            const bool valid = (j0 + j) <= (q0 + r);
            S1s[r][j] = valid ? d1 * scaling : -INFINITY;
            S2s[r][j] = valid ? d2 * scaling : -INFINITY;
        }
        __syncthreads();

        // online-softmax stats: threads 0..31 -> S1 rows, 32..63 -> S2 rows
        if (tid < 2 * QB) {
            const int  r     = tid & 31;
            const bool first = tid < QB;
            float* row = first ? S1s[r] : S2s[r];
            const float mo = first ? m1s[r] : m2s[r];
            const float lo = first ? l1s[r] : l2s[r];
            float tmax = -INFINITY;
            for (int j = 0; j < KB; j++) tmax = fmaxf(tmax, row[j]);
            const float mn = fmaxf(mo, tmax);
            const float c  = expf(mo - mn);      // 0 on first tile (mo=-inf)
            float sum = 0.f;
            for (int j = 0; j < KB; j++) {
                const float p = expf(row[j] - mn);
                row[j] = p;
                sum += p;
            }
            const float ln = lo * c + sum;
            if (first) { m1s[r] = mn; c1s[r] = c; l1s[r] = ln; }
            else       { m2s[r] = mn; c2s[r] = c; l2s[r] = ln; }
        }
        __syncthreads();

        // PV accumulation: thread owns (row r_pv, 8 d-cols starting d0)
        {
            const float cc1 = c1s[r_pv], cc2 = c2s[r_pv];
#pragma unroll
            for (int i = 0; i < 8; i++) { acc1[i] *= cc1; acc2[i] *= cc2; }
            for (int j = 0; j < KB; j++) {
                const float p1 = S1s[r_pv][j];
                const float p2 = S2s[r_pv][j];
                const float4 va = *reinterpret_cast<const float4*>(&vs[j][d0]);
                const float4 vb = *reinterpret_cast<const float4*>(&vs[j][d0 + 4]);
                acc1[0] = fmaf(p1, va.x, acc1[0]); acc2[0] = fmaf(p2, va.x, acc2[0]);
                acc1[1] = fmaf(p1, va.y, acc1[1]); acc2[1] = fmaf(p2, va.y, acc2[1]);
                acc1[2] = fmaf(p1, va.z, acc1[2]); acc2[2] = fmaf(p2, va.z, acc2[2]);
                acc1[3] = fmaf(p1, va.w, acc1[3]); acc2[3] = fmaf(p2, va.w, acc2[3]);
                acc1[4] = fmaf(p1, vb.x, acc1[4]); acc2[4] = fmaf(p2, vb.x, acc2[4]);
                acc1[5] = fmaf(p1, vb.y, acc1[5]); acc2[5] = fmaf(p2, vb.y, acc2[5]);
                acc1[6] = fmaf(p1, vb.z, acc1[6]); acc2[6] = fmaf(p2, vb.z, acc2[6]);
                acc1[7] = fmaf(p1, vb.w, acc1[7]); acc2[7] = fmaf(p2, vb.w, acc2[7]);
            }
        }
    }

    // epilogue: combine softmaxes, RMSNorm over 64 dims, gamma, (1-LI)
    const float il1 = 1.f / l1s[r_pv];
    const float il2 = 1.f / l2s[r_pv];
    float out[8];
    float ss = 0.f;
#pragma unroll
    for (int i = 0; i < 8; i++) {
        const float o = acc1[i] * il1 - lambda_full * (acc2[i] * il2);
        out[i] = o;
        ss += o * o;
    }
    red[dg][r_pv] = ss;
    __syncthreads();
    float tot = 0.f;
#pragma unroll
    for (int g = 0; g < 8; g++) tot += red[g][r_pv];
    const float rs = rsqrtf(tot * (1.f / 64.f) + 1e-5f);
    const float postscale = 1.f - LI;
    float* dst = &normed[(size_t)(q0 + r_pv) * E_DIM + offv + d0];
    float4 o0, o1;
    o0.x = out[0] * rs * gamma[d0 + 0] * postscale;
    o0.y = out[1] * rs * gamma[d0 + 1] * postscale;
    o0.z = out[2] * rs * gamma[d0 + 2] * postscale;
    o0.w = out[3] * rs * gamma[d0 + 3] * postscale;
    o1.x = out[4] * rs * gamma[d0 + 4] * postscale;
    o1.y = out[5] * rs * gamma[d0 + 5] * postscale;
    o1.z = out[6] * rs * gamma[d0 + 6] * postscale;
    o1.w = out[7] * rs * gamma[d0 + 7] * postscale;
    *reinterpret_cast<float4*>(dst)     = o0;
    *reinterpret_cast<float4*>(dst + 4) = o1;
}

// ---------------------------------------------------------------------------
extern "C" void kernel_launch(void* const* d_in, const int* in_sizes, int n_in,
                              void* d_out, int out_size, void* d_ws, size_t ws_size,
                              hipStream_t stream)
{
    const float* x   = (const float*)d_in[0];
    const float* Wq  = (const float*)d_in[1];
    const float* Wk  = (const float*)d_in[2];
    const float* Wv  = (const float*)d_in[3];
    const float* Wo  = (const float*)d_in[4];
    const float* lq1 = (const float*)d_in[5];
    const float* lk1 = (const float*)d_in[6];
    const float* lq2 = (const float*)d_in[7];
    const float* lk2 = (const float*)d_in[8];
    const float* gm  = (const float*)d_in[9];
    float* out = (float*)d_out;

    float* Q   = (float*)d_ws;
    float* K   = Q + (size_t)T_SEQ * E_DIM;
    float* V   = K + (size_t)T_SEQ * E_DIM;
    float* Nrm = V + (size_t)T_SEQ * E_DIM;

    dim3 gqkv(E_DIM / 64, T_SEQ / 64, 3);
    gemm_qkv<<<gqkv, 256, 0, stream>>>(x, Wq, Wk, Wv, Q, K, V,
                                       T_SEQ, E_DIM, E_DIM);

    dim3 gattn(T_SEQ / QB, NH);
    diff_attn<<<gattn, 256, 0, stream>>>(Q, K, V, Nrm, lq1, lk1, lq2, lk2, gm);

    dim3 gout(E_DIM / 64, T_SEQ / 64);
    gemm_one<<<gout, 256, 0, stream>>>(Nrm, Wo, out, T_SEQ, E_DIM, E_DIM);
}

// Round 2
// 613.688 us; speedup vs baseline: 3.6556x; 3.6556x over previous
//
#include <hip/hip_runtime.h>
#include <hip/hip_bf16.h>
#include <math.h>

#define T_SEQ 2048
#define E_DIM 1024
#define NH    16
#define QB    64      // query rows per block (attention)
#define KB    32      // key rows per tile (attention)

__device__ __forceinline__ float4 ldg4(const float* p) {
    return *reinterpret_cast<const float4*>(p);
}

// ---------------------------------------------------------------------------
// C[M,N] = A[M,K] @ W[N,K]^T   (torch Linear), fp32, 64x64 tile, BK=16
// ---------------------------------------------------------------------------
__device__ __forceinline__ void gemm_body(const float* __restrict__ A,
                                          const float* __restrict__ W,
                                          float* __restrict__ C,
                                          int M, int N, int K)
{
    __shared__ float As[16][68];
    __shared__ float Bs[16][68];

    const int tid = threadIdx.x;
    const int tx = tid & 15, ty = tid >> 4;
    const int m0 = blockIdx.y * 64, n0 = blockIdx.x * 64;

    float acc[4][4] = {};

    const int lrow = tid >> 2;
    const int lc4  = (tid & 3) * 4;
    const float* Ag = A + (size_t)(m0 + lrow) * K + lc4;
    const float* Wg = W + (size_t)(n0 + lrow) * K + lc4;

    for (int k0 = 0; k0 < K; k0 += 16) {
        float4 a = ldg4(Ag + k0);
        float4 b = ldg4(Wg + k0);
        __syncthreads();
        As[lc4 + 0][lrow] = a.x; As[lc4 + 1][lrow] = a.y;
        As[lc4 + 2][lrow] = a.z; As[lc4 + 3][lrow] = a.w;
        Bs[lc4 + 0][lrow] = b.x; Bs[lc4 + 1][lrow] = b.y;
        Bs[lc4 + 2][lrow] = b.z; Bs[lc4 + 3][lrow] = b.w;
        __syncthreads();
#pragma unroll
        for (int kk = 0; kk < 16; kk++) {
            const float4 av = *reinterpret_cast<const float4*>(&As[kk][ty * 4]);
            const float4 bv = *reinterpret_cast<const float4*>(&Bs[kk][tx * 4]);
            const float a4[4] = {av.x, av.y, av.z, av.w};
            const float b4[4] = {bv.x, bv.y, bv.z, bv.w};
#pragma unroll
            for (int i = 0; i < 4; i++)
#pragma unroll
                for (int j = 0; j < 4; j++)
                    acc[i][j] = fmaf(a4[i], b4[j], acc[i][j]);
        }
    }

#pragma unroll
    for (int i = 0; i < 4; i++) {
        float4 o;
        o.x = acc[i][0]; o.y = acc[i][1]; o.z = acc[i][2]; o.w = acc[i][3];
        *reinterpret_cast<float4*>(&C[(size_t)(m0 + ty * 4 + i) * N + n0 + tx * 4]) = o;
    }
}

__global__ __launch_bounds__(256)
void gemm_qkv(const float* __restrict__ A,
              const float* __restrict__ W0, const float* __restrict__ W1,
              const float* __restrict__ W2,
              float* __restrict__ C0, float* __restrict__ C1, float* __restrict__ C2,
              int M, int N, int K)
{
    const float* W = (blockIdx.z == 0) ? W0 : (blockIdx.z == 1) ? W1 : W2;
    float*       C = (blockIdx.z == 0) ? C0 : (blockIdx.z == 1) ? C1 : C2;
    gemm_body(A, W, C, M, N, K);
}

__global__ __launch_bounds__(256)
void gemm_one(const float* __restrict__ A, const float* __restrict__ W,
              float* __restrict__ C, int M, int N, int K)
{
    gemm_body(A, W, C, M, N, K);
}

// ---------------------------------------------------------------------------
// Differential attention v2: register-blocked scores, wave-parallel softmax,
// register-blocked PV, fused RMSNorm epilogue.
// Grid: flat 512 blocks (32 q-blocks x 16 heads, balance-remapped), 256 thr.
// ---------------------------------------------------------------------------
__global__ __launch_bounds__(256)
void diff_attn2(const float* __restrict__ Q, const float* __restrict__ Km,
                const float* __restrict__ V, float* __restrict__ normed,
                const float* __restrict__ lq1, const float* __restrict__ lk1,
                const float* __restrict__ lq2, const float* __restrict__ lk2,
                const float* __restrict__ gamma)
{
    __shared__ float qT[64][68];   // [k-dim (2 subs x 32)][row], pre-scaled
    __shared__ float kT[64][36];   // [k-dim][key j]
    __shared__ float vs[KB][68];   // [key j][d 0..63]
    __shared__ float ST[64][68];   // [col = sub*32 + j][row]
    __shared__ float m_s[QB][2], l_s[QB][2], c_s[QB][2];

    const int tid = threadIdx.x;
    const int u  = blockIdx.x >> 4;          // 0..31
    const int h  = blockIdx.x & 15;
    const int qb = (u < 16) ? u : 47 - u;    // balance: pair weights sum const
    const int q0 = qb * QB;
    const int off1 = h * 64;                 // q/k sub1 at off1, sub2 at off1+32; v at off1
    const float scaling = 0.17677669529663687f;   // 32^-0.5
    const float LI = 0.4707130183435841f;         // 0.8 - 0.6*exp(-0.6)

    float s1 = 0.f, s2 = 0.f;
#pragma unroll
    for (int i = 0; i < 32; i++) {
        s1 += lq1[i] * lk1[i];
        s2 += lq2[i] * lk2[i];
    }
    const float lambda_full = expf(s1) - expf(s2) + LI;

    // stage qT transposed, scaling folded in
#pragma unroll
    for (int p = 0; p < 4; p++) {
        const int f = tid + p * 256;
        const int row = f >> 4, c4 = (f & 15) * 4;
        float4 a = ldg4(&Q[(size_t)(q0 + row) * E_DIM + off1 + c4]);
        qT[c4 + 0][row] = a.x * scaling; qT[c4 + 1][row] = a.y * scaling;
        qT[c4 + 2][row] = a.z * scaling; qT[c4 + 3][row] = a.w * scaling;
    }
    if (tid < 128) {
        const int r = tid >> 1, s = tid & 1;
        m_s[r][s] = -INFINITY; l_s[r][s] = 0.f;
    }

    float acc[2][4][4] = {};
    const int ty   = tid >> 4;        // 0..15: row group (score + PV)
    const int tx   = tid & 15;
    const int ssub = tx >> 3;         // score: which subhead
    const int j4   = (tx & 7) * 4;    // score: col group within sub
    const int rg4  = ty * 4;
    const int dg4  = tx * 4;          // PV: dim group
    const int r_sm = tid >> 2, sub_sm = (tid >> 1) & 1, half_sm = tid & 1;

    const int nkb = 2 * qb + 2;
    for (int kb = 0; kb < nkb; kb++) {
        const int j0 = kb * KB;
        __syncthreads();   // prev PV done reading vs/ST
        // stage kT (transposed) + vs
#pragma unroll
        for (int p = 0; p < 2; p++) {
            const int f = tid + p * 256;
            const int row = f >> 4, c4 = (f & 15) * 4;
            float4 a = ldg4(&Km[(size_t)(j0 + row) * E_DIM + off1 + c4]);
            kT[c4 + 0][row] = a.x; kT[c4 + 1][row] = a.y;
            kT[c4 + 2][row] = a.z; kT[c4 + 3][row] = a.w;
            float4 b = ldg4(&V[(size_t)(j0 + row) * E_DIM + off1 + c4]);
            *reinterpret_cast<float4*>(&vs[row][c4]) = b;
        }
        __syncthreads();

        // ---- scores: 4x4 per thread, one subhead ----
        float sc[4][4] = {};
#pragma unroll 8
        for (int kk = 0; kk < 32; kk++) {
            const float4 qv = *reinterpret_cast<const float4*>(&qT[ssub * 32 + kk][rg4]);
            const float4 kv = *reinterpret_cast<const float4*>(&kT[ssub * 32 + kk][j4]);
            const float qa[4] = {qv.x, qv.y, qv.z, qv.w};
            const float ka[4] = {kv.x, kv.y, kv.z, kv.w};
#pragma unroll
            for (int i = 0; i < 4; i++)
#pragma unroll
                for (int j = 0; j < 4; j++)
                    sc[i][j] = fmaf(qa[i], ka[j], sc[i][j]);
        }
        // masked transpose-write to ST[col][row]
#pragma unroll
        for (int j = 0; j < 4; j++) {
            float4 cvec;
            float* cp = &cvec.x;
#pragma unroll
            for (int i = 0; i < 4; i++) {
                const bool valid = (j0 + j4 + j) <= (q0 + rg4 + i);
                cp[i] = valid ? sc[i][j] : -INFINITY;
            }
            *reinterpret_cast<float4*>(&ST[ssub * 32 + j4 + j][rg4]) = cvec;
        }
        __syncthreads();

        // ---- wave-parallel online softmax: thread = (row, sub, half) ----
        {
            const int r = r_sm, sb = sub_sm, hf = half_sm;
            float mloc = -INFINITY;
#pragma unroll
            for (int jj = 0; jj < 16; jj++) {
                const int j = hf * 16 + ((jj + 4 * hf) & 15);  // bank rotation
                mloc = fmaxf(mloc, ST[sb * 32 + j][r]);
            }
            mloc = fmaxf(mloc, __shfl_xor(mloc, 1));
            const float mold = m_s[r][sb];
            const float mn = fmaxf(mold, mloc);
            const float corr = __expf(mold - mn);
            float sum = 0.f;
#pragma unroll
            for (int jj = 0; jj < 16; jj++) {
                const int j = hf * 16 + ((jj + 4 * hf) & 15);
                const float p = __expf(ST[sb * 32 + j][r] - mn);
                ST[sb * 32 + j][r] = p;
                sum += p;
            }
            sum += __shfl_xor(sum, 1);
            if (hf == 0) {
                m_s[r][sb] = mn;
                c_s[r][sb] = corr;
                l_s[r][sb] = l_s[r][sb] * corr + sum;
            }
        }
        __syncthreads();

        // ---- PV: 4 rows x 4 dims x 2 subs per thread ----
        {
            float c1[4], c2[4];
#pragma unroll
            for (int rr = 0; rr < 4; rr++) {
                c1[rr] = c_s[rg4 + rr][0];
                c2[rr] = c_s[rg4 + rr][1];
            }
#pragma unroll
            for (int rr = 0; rr < 4; rr++)
#pragma unroll
                for (int dd = 0; dd < 4; dd++) {
                    acc[0][rr][dd] *= c1[rr];
                    acc[1][rr][dd] *= c2[rr];
                }
#pragma unroll 4
            for (int j = 0; j < KB; j++) {
                const float4 p1 = *reinterpret_cast<const float4*>(&ST[j][rg4]);
                const float4 p2 = *reinterpret_cast<const float4*>(&ST[32 + j][rg4]);
                const float4 vv = *reinterpret_cast<const float4*>(&vs[j][dg4]);
                const float pa[4] = {p1.x, p1.y, p1.z, p1.w};
                const float pb[4] = {p2.x, p2.y, p2.z, p2.w};
                const float va[4] = {vv.x, vv.y, vv.z, vv.w};
#pragma unroll
                for (int rr = 0; rr < 4; rr++)
#pragma unroll
                    for (int dd = 0; dd < 4; dd++) {
                        acc[0][rr][dd] = fmaf(pa[rr], va[dd], acc[0][rr][dd]);
                        acc[1][rr][dd] = fmaf(pb[rr], va[dd], acc[1][rr][dd]);
                    }
            }
        }
    }

    // ---- epilogue: combine, RMSNorm(64), gamma, (1-LI) ----
    float g4[4];
#pragma unroll
    for (int i = 0; i < 4; i++) g4[i] = gamma[dg4 + i];
    const float postscale = 1.f - LI;
#pragma unroll
    for (int rr = 0; rr < 4; rr++) {
        const float il1 = 1.f / l_s[rg4 + rr][0];
        const float il2 = lambda_full / l_s[rg4 + rr][1];
        float o[4];
        float ss = 0.f;
#pragma unroll
        for (int dd = 0; dd < 4; dd++) {
            o[dd] = acc[0][rr][dd] * il1 - acc[1][rr][dd] * il2;
            ss = fmaf(o[dd], o[dd], ss);
        }
        ss += __shfl_xor(ss, 1); ss += __shfl_xor(ss, 2);
        ss += __shfl_xor(ss, 4); ss += __shfl_xor(ss, 8);
        const float rs = rsqrtf(ss * (1.f / 64.f) + 1e-5f);
        float4 ov;
        ov.x = o[0] * rs * g4[0] * postscale;
        ov.y = o[1] * rs * g4[1] * postscale;
        ov.z = o[2] * rs * g4[2] * postscale;
        ov.w = o[3] * rs * g4[3] * postscale;
        *reinterpret_cast<float4*>(&normed[(size_t)(q0 + rg4 + rr) * E_DIM + off1 + dg4]) = ov;
    }
}

// ---------------------------------------------------------------------------
extern "C" void kernel_launch(void* const* d_in, const int* in_sizes, int n_in,
                              void* d_out, int out_size, void* d_ws, size_t ws_size,
                              hipStream_t stream)
{
    const float* x   = (const float*)d_in[0];
    const float* Wq  = (const float*)d_in[1];
    const float* Wk  = (const float*)d_in[2];
    const float* Wv  = (const float*)d_in[3];
    const float* Wo  = (const float*)d_in[4];
    const float* lq1 = (const float*)d_in[5];
    const float* lk1 = (const float*)d_in[6];
    const float* lq2 = (const float*)d_in[7];
    const float* lk2 = (const float*)d_in[8];
    const float* gm  = (const float*)d_in[9];
    float* out = (float*)d_out;

    float* Q   = (float*)d_ws;
    float* K   = Q + (size_t)T_SEQ * E_DIM;
    float* V   = K + (size_t)T_SEQ * E_DIM;
    float* Nrm = V + (size_t)T_SEQ * E_DIM;

    dim3 gqkv(E_DIM / 64, T_SEQ / 64, 3);
    gemm_qkv<<<gqkv, 256, 0, stream>>>(x, Wq, Wk, Wv, Q, K, V,
                                       T_SEQ, E_DIM, E_DIM);

    diff_attn2<<<(T_SEQ / QB) * NH, 256, 0, stream>>>(Q, K, V, Nrm,
                                                      lq1, lk1, lq2, lk2, gm);

    dim3 gout(E_DIM / 64, T_SEQ / 64);
    gemm_one<<<gout, 256, 0, stream>>>(Nrm, Wo, out, T_SEQ, E_DIM, E_DIM);
}

// Round 5
// 195.486 us; speedup vs baseline: 11.4761x; 3.1393x over previous
//
#include <hip/hip_runtime.h>
#include <math.h>

typedef float f32x4 __attribute__((ext_vector_type(4)));
typedef __bf16 bf16x8 __attribute__((ext_vector_type(8)));

#define MFMA16(a, b, c) __builtin_amdgcn_mfma_f32_16x16x32_bf16((a), (b), (c), 0, 0, 0)

__device__ __forceinline__ unsigned short f2bf(float f) {
    union { float f; unsigned u; } v; v.f = f;
    return (unsigned short)((v.u + 0x7fffu + ((v.u >> 16) & 1u)) >> 16);
}
__device__ __forceinline__ unsigned pack2(float a, float b) {
    return (unsigned)f2bf(a) | ((unsigned)f2bf(b) << 16);
}

// ---------------------------------------------------------------------------
// fp32 -> bf16 conversion of x and the 4 weight matrices. 1 float4 per thread.
// ---------------------------------------------------------------------------
__global__ __launch_bounds__(256)
void convert_bf16(const float* __restrict__ x,  const float* __restrict__ wq,
                  const float* __restrict__ wk, const float* __restrict__ wv,
                  const float* __restrict__ wo,
                  unsigned short* __restrict__ xb,  unsigned short* __restrict__ wqb,
                  unsigned short* __restrict__ wkb, unsigned short* __restrict__ wvb,
                  unsigned short* __restrict__ wob)
{
    int i = blockIdx.x * 256 + threadIdx.x;     // grid covers 1572864 float4 units
    const float* s; unsigned short* d; int o;
    if (i < 524288)       { s = x;  d = xb;  o = i; }
    else if (i < 786432)  { s = wq; d = wqb; o = i - 524288; }
    else if (i < 1048576) { s = wk; d = wkb; o = i - 786432; }
    else if (i < 1310720) { s = wv; d = wvb; o = i - 1048576; }
    else                  { s = wo; d = wob; o = i - 1310720; }
    float4 v = *reinterpret_cast<const float4*>(s + (size_t)o * 4);
    ushort4 r;
    r.x = f2bf(v.x); r.y = f2bf(v.y); r.z = f2bf(v.z); r.w = f2bf(v.w);
    *reinterpret_cast<ushort4*>(d + (size_t)o * 4) = r;
}

// ---------------------------------------------------------------------------
// C[2048,1024] = A[2048,1024] @ W[1024,1024]^T in bf16 MFMA.
// Tile 128x64, BK=64, 4 waves (2x2), wave tile 64x32.
// mode 0: C bf16 [M,N]; mode 1: C bf16 transposed [N,M]; mode 2: C f32 [M,N].
// LDS XOR-swizzled (byte ^= (row&7)<<4) so frag ds_read_b128 is conflict-free.
// ---------------------------------------------------------------------------
__device__ __forceinline__ void gemm_bf16_body(const unsigned short* __restrict__ A,
                                               const unsigned short* __restrict__ W,
                                               void* __restrict__ Cp, int mode)
{
    __shared__ char Al[128 * 128];   // 128 rows x 64 bf16
    __shared__ char Bl[64 * 128];    // 64 rows x 64 bf16

    const int tid = threadIdx.x;
    const int lane = tid & 63, w = tid >> 6;
    const int g = lane >> 4, r15 = lane & 15;
    const int wm = (w >> 1) * 64, wn = (w & 1) * 32;
    const int m0 = blockIdx.y * 128, n0 = blockIdx.x * 64;

    f32x4 acc[4][2] = {};

    for (int k0 = 0; k0 < 1024; k0 += 64) {
        __syncthreads();
#pragma unroll
        for (int p = 0; p < 4; p++) {
            int idx = p * 256 + tid;
            int row = idx >> 3, c8 = idx & 7;
            bf16x8 v = *reinterpret_cast<const bf16x8*>(A + (size_t)(m0 + row) * 1024 + k0 + c8 * 8);
            int byte = (row * 128 + c8 * 16) ^ ((row & 7) << 4);
            *reinterpret_cast<bf16x8*>(Al + byte) = v;
        }
#pragma unroll
        for (int p = 0; p < 2; p++) {
            int idx = p * 256 + tid;
            int row = idx >> 3, c8 = idx & 7;
            bf16x8 v = *reinterpret_cast<const bf16x8*>(W + (size_t)(n0 + row) * 1024 + k0 + c8 * 8);
            int byte = (row * 128 + c8 * 16) ^ ((row & 7) << 4);
            *reinterpret_cast<bf16x8*>(Bl + byte) = v;
        }
        __syncthreads();
#pragma unroll
        for (int c = 0; c < 2; c++) {
            bf16x8 af[4], bfr[2];
#pragma unroll
            for (int m = 0; m < 4; m++) {
                int row = wm + m * 16 + r15;
                int byte = (row * 128 + g * 16 + c * 64) ^ ((row & 7) << 4);
                af[m] = *reinterpret_cast<const bf16x8*>(Al + byte);
            }
#pragma unroll
            for (int n = 0; n < 2; n++) {
                int row = wn + n * 16 + r15;
                int byte = (row * 128 + g * 16 + c * 64) ^ ((row & 7) << 4);
                bfr[n] = *reinterpret_cast<const bf16x8*>(Bl + byte);
            }
#pragma unroll
            for (int m = 0; m < 4; m++)
#pragma unroll
                for (int n = 0; n < 2; n++)
                    acc[m][n] = MFMA16(af[m], bfr[n], acc[m][n]);
        }
    }

    if (mode == 0) {
        unsigned short* C = (unsigned short*)Cp;
#pragma unroll
        for (int m = 0; m < 4; m++)
#pragma unroll
            for (int n = 0; n < 2; n++)
#pragma unroll
                for (int i = 0; i < 4; i++)
                    C[(size_t)(m0 + wm + m * 16 + g * 4 + i) * 1024 + n0 + wn + n * 16 + r15] =
                        f2bf(acc[m][n][i]);
    } else if (mode == 1) {
        unsigned short* C = (unsigned short*)Cp;   // Ct[1024][2048]
#pragma unroll
        for (int m = 0; m < 4; m++)
#pragma unroll
            for (int n = 0; n < 2; n++) {
                unsigned long long v = (unsigned long long)pack2(acc[m][n][0], acc[m][n][1])
                                     | ((unsigned long long)pack2(acc[m][n][2], acc[m][n][3]) << 32);
                *reinterpret_cast<unsigned long long*>(
                    C + (size_t)(n0 + wn + n * 16 + r15) * 2048 + m0 + wm + m * 16 + g * 4) = v;
            }
    } else {
        float* C = (float*)Cp;
#pragma unroll
        for (int m = 0; m < 4; m++)
#pragma unroll
            for (int n = 0; n < 2; n++)
#pragma unroll
                for (int i = 0; i < 4; i++)
                    C[(size_t)(m0 + wm + m * 16 + g * 4 + i) * 1024 + n0 + wn + n * 16 + r15] =
                        acc[m][n][i];
    }
}

__global__ __launch_bounds__(256)
void gemm_qkv_bf16(const unsigned short* __restrict__ xb, const unsigned short* __restrict__ wqb,
                   const unsigned short* __restrict__ wkb, const unsigned short* __restrict__ wvb,
                   unsigned short* __restrict__ Qb, unsigned short* __restrict__ Kb,
                   unsigned short* __restrict__ Vtb)
{
    int z = blockIdx.z;
    const unsigned short* W = (z == 0) ? wqb : (z == 1) ? wkb : wvb;
    void* C = (z == 0) ? (void*)Qb : (z == 1) ? (void*)Kb : (void*)Vtb;
    gemm_bf16_body(xb, W, C, (z == 2) ? 1 : 0);
}

__global__ __launch_bounds__(256)
void gemm_out_bf16(const unsigned short* __restrict__ Nb, const unsigned short* __restrict__ wob,
                   float* __restrict__ out)
{
    gemm_bf16_body(Nb, wob, out, 2);
}

// ---------------------------------------------------------------------------
// Differential attention, MFMA version.
// Swapped score MFMA: T = K_tile (A) x Q (B)  => lane owns one q-row (col),
// keys spread over 4 lane-groups (16 keys in-lane) -> softmax = in-lane + 2 shfl.
// P repacked bf16 -> wave-local swizzled LDS -> re-read as PV A-fragments.
// Grid: 512 blocks (32 q-blocks x 16 heads, balance-remapped), 256 threads.
// ---------------------------------------------------------------------------
__global__ __launch_bounds__(256)
void attn_mfma(const unsigned short* __restrict__ Qb, const unsigned short* __restrict__ Kb,
               const unsigned short* __restrict__ Vtb, unsigned short* __restrict__ Nb,
               const float* __restrict__ lq1, const float* __restrict__ lk1,
               const float* __restrict__ lq2, const float* __restrict__ lk2,
               const float* __restrict__ gamma)
{
    __shared__ char Kl[64 * 128];      // [key][hd 0..63] bf16, swizzled
    __shared__ char Vl[64 * 128];      // [dim][key 0..63] bf16, swizzled
    __shared__ char Pl[2][64 * 128];   // [sub][q-row][key] bf16, swizzled (wave-local rows)

    const int tid = threadIdx.x, lane = tid & 63, w = tid >> 6;
    const int g = lane >> 4, r15 = lane & 15;
    const int u = blockIdx.x >> 4, h = blockIdx.x & 15;
    const int qb = (u < 16) ? u : 47 - u;   // causal load-balance pairing
    const int q0 = qb * 64;
    const int row_g = q0 + w * 16 + r15;    // this lane's q-row

    float s1 = 0.f, s2 = 0.f;
#pragma unroll
    for (int i = 0; i < 32; i++) { s1 += lq1[i] * lk1[i]; s2 += lq2[i] * lk2[i]; }
    const float LI = 0.4707130183435841f;          // 0.8 - 0.6*exp(-0.6)
    const float lam = expf(s1) - expf(s2) + LI;
    const float scale = 0.17677669529663687f;      // 32^-0.5

    // Q as score-MFMA B-operand: loaded once, reused for all tiles.
    bf16x8 qf0 = *reinterpret_cast<const bf16x8*>(Qb + (size_t)row_g * 1024 + h * 64 + g * 8);
    bf16x8 qf1 = *reinterpret_cast<const bf16x8*>(Qb + (size_t)row_g * 1024 + h * 64 + 32 + g * 8);

    f32x4 oacc[2][4] = {};
    float m_r[2] = {-INFINITY, -INFINITY};
    float l_r[2] = {0.f, 0.f};

    for (int kb = 0; kb <= qb; kb++) {
        const int j0 = kb * 64;
        __syncthreads();
#pragma unroll
        for (int p = 0; p < 2; p++) {
            int idx = p * 256 + tid;
            int row = idx >> 3, c8 = idx & 7;
            bf16x8 v = *reinterpret_cast<const bf16x8*>(Kb + (size_t)(j0 + row) * 1024 + h * 64 + c8 * 8);
            int byte = (row * 128 + c8 * 16) ^ ((row & 7) << 4);
            *reinterpret_cast<bf16x8*>(Kl + byte) = v;
        }
#pragma unroll
        for (int p = 0; p < 2; p++) {
            int idx = p * 256 + tid;
            int row = idx >> 3, c8 = idx & 7;
            bf16x8 v = *reinterpret_cast<const bf16x8*>(Vtb + (size_t)(h * 64 + row) * 2048 + j0 + c8 * 8);
            int byte = (row * 128 + c8 * 16) ^ ((row & 7) << 4);
            *reinterpret_cast<bf16x8*>(Vl + byte) = v;
        }
        __syncthreads();

        // scores: T = K . Q^T  (keys = M-frags, q-rows = N)
        f32x4 sc0[4] = {}, sc1[4] = {};
#pragma unroll
        for (int m = 0; m < 4; m++) {
            int row = m * 16 + r15;
            int b0 = (row * 128 + g * 16) ^ ((row & 7) << 4);
            int b1 = (row * 128 + g * 16 + 64) ^ ((row & 7) << 4);
            bf16x8 a0 = *reinterpret_cast<const bf16x8*>(Kl + b0);
            bf16x8 a1 = *reinterpret_cast<const bf16x8*>(Kl + b1);
            sc0[m] = MFMA16(a0, qf0, sc0[m]);
            sc1[m] = MFMA16(a1, qf1, sc1[m]);
        }

        const bool diag = (kb == qb);
        float corr[2];
#pragma unroll
        for (int s = 0; s < 2; s++) {
            f32x4* sc = s ? sc1 : sc0;
            float sv[4][4];
            float mx = -INFINITY;
#pragma unroll
            for (int m = 0; m < 4; m++)
#pragma unroll
                for (int i = 0; i < 4; i++) {
                    float xv = sc[m][i] * scale;
                    if (diag && (j0 + m * 16 + g * 4 + i) > row_g) xv = -INFINITY;
                    sv[m][i] = xv;
                    mx = fmaxf(mx, xv);
                }
            mx = fmaxf(mx, __shfl_xor(mx, 16));
            mx = fmaxf(mx, __shfl_xor(mx, 32));
            const float mn = fmaxf(m_r[s], mx);
            corr[s] = __expf(m_r[s] - mn);
            m_r[s] = mn;
            float sum = 0.f;
            const int prow = w * 16 + r15;
#pragma unroll
            for (int m = 0; m < 4; m++) {
                float p0 = __expf(sv[m][0] - mn);
                float p1 = __expf(sv[m][1] - mn);
                float p2 = __expf(sv[m][2] - mn);
                float p3 = __expf(sv[m][3] - mn);
                sum += (p0 + p1) + (p2 + p3);
                unsigned long long pv = (unsigned long long)pack2(p0, p1)
                                      | ((unsigned long long)pack2(p2, p3) << 32);
                int byte = (prow * 128 + m * 32 + g * 8) ^ ((prow & 7) << 4);
                *reinterpret_cast<unsigned long long*>(Pl[s] + byte) = pv;
            }
            sum += __shfl_xor(sum, 16);
            sum += __shfl_xor(sum, 32);
            l_r[s] = l_r[s] * corr[s] + sum;
        }

        // rescale O accumulators (accs are row = g*4+i; corr lives at lane r15=row)
        float c0[4], c1v[4];
#pragma unroll
        for (int i = 0; i < 4; i++) {
            c0[i]  = __shfl(corr[0], g * 4 + i);
            c1v[i] = __shfl(corr[1], g * 4 + i);
        }
#pragma unroll
        for (int n = 0; n < 4; n++)
#pragma unroll
            for (int i = 0; i < 4; i++) {
                oacc[0][n][i] *= c0[i];
                oacc[1][n][i] *= c1v[i];
            }

        // PV: O += P . V   (wave-local Pl re-read as A-frags; Vl rows as B-frags)
#pragma unroll
        for (int c = 0; c < 2; c++) {
            const int prow = w * 16 + r15;
            int pb = (prow * 128 + g * 16 + c * 64) ^ ((prow & 7) << 4);
            bf16x8 p0 = *reinterpret_cast<const bf16x8*>(Pl[0] + pb);
            bf16x8 p1 = *reinterpret_cast<const bf16x8*>(Pl[1] + pb);
#pragma unroll
            for (int n = 0; n < 4; n++) {
                int vrow = n * 16 + r15;
                int vb = (vrow * 128 + g * 16 + c * 64) ^ ((vrow & 7) << 4);
                bf16x8 vf = *reinterpret_cast<const bf16x8*>(Vl + vb);
                oacc[0][n] = MFMA16(p0, vf, oacc[0][n]);
                oacc[1][n] = MFMA16(p1, vf, oacc[1][n]);
            }
        }
    }

    // epilogue: combine subheads, RMSNorm over 64 dims, gamma, (1-LI), bf16 store
    float i1[4], i2[4];
    {
        float r1 = 1.f / l_r[0];
        float r2 = lam / l_r[1];
#pragma unroll
        for (int i = 0; i < 4; i++) {
            i1[i] = __shfl(r1, g * 4 + i);
            i2[i] = __shfl(r2, g * 4 + i);
        }
    }
    float o[4][4], ss[4] = {0.f, 0.f, 0.f, 0.f};
#pragma unroll
    for (int n = 0; n < 4; n++)
#pragma unroll
        for (int i = 0; i < 4; i++) {
            float v = oacc[0][n][i] * i1[i] - oacc[1][n][i] * i2[i];
            o[n][i] = v;
            ss[i] = fmaf(v, v, ss[i]);
        }
#pragma unroll
    for (int i = 0; i < 4; i++) {
        ss[i] += __shfl_xor(ss[i], 1);
        ss[i] += __shfl_xor(ss[i], 2);
        ss[i] += __shfl_xor(ss[i], 4);
        ss[i] += __shfl_xor(ss[i], 8);
    }
    const float post = 1.f - LI;
    float gm4[4];
#pragma unroll
    for (int n = 0; n < 4; n++) gm4[n] = gamma[n * 16 + r15];
#pragma unroll
    for (int i = 0; i < 4; i++) {
        const float rs = rsqrtf(ss[i] * 0.015625f + 1e-5f);
#pragma unroll
        for (int n = 0; n < 4; n++) {
            Nb[(size_t)(q0 + w * 16 + g * 4 + i) * 1024 + h * 64 + n * 16 + r15] =
                f2bf(o[n][i] * rs * gm4[n] * post);
        }
    }
}

// ---------------------------------------------------------------------------
extern "C" void kernel_launch(void* const* d_in, const int* in_sizes, int n_in,
                              void* d_out, int out_size, void* d_ws, size_t ws_size,
                              hipStream_t stream)
{
    const float* x   = (const float*)d_in[0];
    const float* Wq  = (const float*)d_in[1];
    const float* Wk  = (const float*)d_in[2];
    const float* Wv  = (const float*)d_in[3];
    const float* Wo  = (const float*)d_in[4];
    const float* lq1 = (const float*)d_in[5];
    const float* lk1 = (const float*)d_in[6];
    const float* lq2 = (const float*)d_in[7];
    const float* lk2 = (const float*)d_in[8];
    const float* gm  = (const float*)d_in[9];
    float* out = (float*)d_out;

    unsigned short* ws  = (unsigned short*)d_ws;
    unsigned short* xb  = ws;               // 2M elts
    unsigned short* wqb = xb  + 2097152;    // 1M
    unsigned short* wkb = wqb + 1048576;    // 1M
    unsigned short* wvb = wkb + 1048576;    // 1M
    unsigned short* wob = wvb + 1048576;    // 1M
    unsigned short* Qb  = wob + 1048576;    // 2M
    unsigned short* Kb  = Qb  + 2097152;    // 2M
    unsigned short* Vtb = Kb  + 2097152;    // 2M [1024 dims][2048 seq]
    unsigned short* Nb  = Vtb + 2097152;    // 2M

    convert_bf16<<<6144, 256, 0, stream>>>(x, Wq, Wk, Wv, Wo, xb, wqb, wkb, wvb, wob);
    gemm_qkv_bf16<<<dim3(16, 16, 3), 256, 0, stream>>>(xb, wqb, wkb, wvb, Qb, Kb, Vtb);
    attn_mfma<<<512, 256, 0, stream>>>(Qb, Kb, Vtb, Nb, lq1, lk1, lq2, lk2, gm);
    gemm_out_bf16<<<dim3(16, 16), 256, 0, stream>>>(Nb, wob, out);
}

// Round 8
// 192.018 us; speedup vs baseline: 11.6834x; 1.0181x over previous
//
#include <hip/hip_runtime.h>
#include <math.h>

typedef float f32x4 __attribute__((ext_vector_type(4)));
typedef __bf16 bf16x8 __attribute__((ext_vector_type(8)));

#define MFMA16(a, b, c) __builtin_amdgcn_mfma_f32_16x16x32_bf16((a), (b), (c), 0, 0, 0)

__device__ __forceinline__ unsigned short f2bf(float f) {
    union { float f; unsigned u; } v; v.f = f;
    return (unsigned short)((v.u + 0x7fffu + ((v.u >> 16) & 1u)) >> 16);
}
__device__ __forceinline__ unsigned pack2(float a, float b) {
    return (unsigned)f2bf(a) | ((unsigned)f2bf(b) << 16);
}

// ---------------------------------------------------------------------------
// fp32 -> bf16 conversion of x and the 4 weight matrices. 1 float4 per thread.
// ---------------------------------------------------------------------------
__global__ __launch_bounds__(256)
void convert_bf16(const float* __restrict__ x,  const float* __restrict__ wq,
                  const float* __restrict__ wk, const float* __restrict__ wv,
                  const float* __restrict__ wo,
                  unsigned short* __restrict__ xb,  unsigned short* __restrict__ wqb,
                  unsigned short* __restrict__ wkb, unsigned short* __restrict__ wvb,
                  unsigned short* __restrict__ wob)
{
    int i = blockIdx.x * 256 + threadIdx.x;     // grid covers 1572864 float4 units
    const float* s; unsigned short* d; int o;
    if (i < 524288)       { s = x;  d = xb;  o = i; }
    else if (i < 786432)  { s = wq; d = wqb; o = i - 524288; }
    else if (i < 1048576) { s = wk; d = wkb; o = i - 786432; }
    else if (i < 1310720) { s = wv; d = wvb; o = i - 1048576; }
    else                  { s = wo; d = wob; o = i - 1310720; }
    float4 v = *reinterpret_cast<const float4*>(s + (size_t)o * 4);
    ushort4 r;
    r.x = f2bf(v.x); r.y = f2bf(v.y); r.z = f2bf(v.z); r.w = f2bf(v.w);
    *reinterpret_cast<ushort4*>(d + (size_t)o * 4) = r;
}

// ---------------------------------------------------------------------------
// C[2048,1024] = A[2048,1024] @ W[1024,1024]^T in bf16 MFMA.
// Tile 128x64, BK=64, 4 waves (2x2), wave tile 64x32.
// mode 0: C bf16; mode 1: C bf16 transposed [N,M]; mode 2: C f32;
// mode 3: C bf16 scaled by (hd^-0.5 * log2(e))  [Q prescale for exp2 softmax]
// LDS XOR-swizzled (byte ^= (row&7)<<4) so frag ds_read_b128 is conflict-free.
// ---------------------------------------------------------------------------
__device__ __forceinline__ void gemm_bf16_body(const unsigned short* __restrict__ A,
                                               const unsigned short* __restrict__ W,
                                               void* __restrict__ Cp, int mode)
{
    __shared__ char Al[128 * 128];   // 128 rows x 64 bf16
    __shared__ char Bl[64 * 128];    // 64 rows x 64 bf16

    const int tid = threadIdx.x;
    const int lane = tid & 63, w = tid >> 6;
    const int g = lane >> 4, r15 = lane & 15;
    const int wm = (w >> 1) * 64, wn = (w & 1) * 32;
    const int m0 = blockIdx.y * 128, n0 = blockIdx.x * 64;

    f32x4 acc[4][2] = {};

    for (int k0 = 0; k0 < 1024; k0 += 64) {
        __syncthreads();
#pragma unroll
        for (int p = 0; p < 4; p++) {
            int idx = p * 256 + tid;
            int row = idx >> 3, c8 = idx & 7;
            bf16x8 v = *reinterpret_cast<const bf16x8*>(A + (size_t)(m0 + row) * 1024 + k0 + c8 * 8);
            int byte = (row * 128 + c8 * 16) ^ ((row & 7) << 4);
            *reinterpret_cast<bf16x8*>(Al + byte) = v;
        }
#pragma unroll
        for (int p = 0; p < 2; p++) {
            int idx = p * 256 + tid;
            int row = idx >> 3, c8 = idx & 7;
            bf16x8 v = *reinterpret_cast<const bf16x8*>(W + (size_t)(n0 + row) * 1024 + k0 + c8 * 8);
            int byte = (row * 128 + c8 * 16) ^ ((row & 7) << 4);
            *reinterpret_cast<bf16x8*>(Bl + byte) = v;
        }
        __syncthreads();
#pragma unroll
        for (int c = 0; c < 2; c++) {
            bf16x8 af[4], bfr[2];
#pragma unroll
            for (int m = 0; m < 4; m++) {
                int row = wm + m * 16 + r15;
                int byte = (row * 128 + g * 16 + c * 64) ^ ((row & 7) << 4);
                af[m] = *reinterpret_cast<const bf16x8*>(Al + byte);
            }
#pragma unroll
            for (int n = 0; n < 2; n++) {
                int row = wn + n * 16 + r15;
                int byte = (row * 128 + g * 16 + c * 64) ^ ((row & 7) << 4);
                bfr[n] = *reinterpret_cast<const bf16x8*>(Bl + byte);
            }
#pragma unroll
            for (int m = 0; m < 4; m++)
#pragma unroll
                for (int n = 0; n < 2; n++)
                    acc[m][n] = MFMA16(af[m], bfr[n], acc[m][n]);
        }
    }

    if (mode == 0 || mode == 3) {
        const float cs = (mode == 3) ? 0.25504190132624806f : 1.0f;  // 32^-0.5 * log2(e)
        unsigned short* C = (unsigned short*)Cp;
#pragma unroll
        for (int m = 0; m < 4; m++)
#pragma unroll
            for (int n = 0; n < 2; n++)
#pragma unroll
                for (int i = 0; i < 4; i++)
                    C[(size_t)(m0 + wm + m * 16 + g * 4 + i) * 1024 + n0 + wn + n * 16 + r15] =
                        f2bf(acc[m][n][i] * cs);
    } else if (mode == 1) {
        unsigned short* C = (unsigned short*)Cp;   // Ct[1024][2048]
#pragma unroll
        for (int m = 0; m < 4; m++)
#pragma unroll
            for (int n = 0; n < 2; n++) {
                unsigned long long v = (unsigned long long)pack2(acc[m][n][0], acc[m][n][1])
                                     | ((unsigned long long)pack2(acc[m][n][2], acc[m][n][3]) << 32);
                *reinterpret_cast<unsigned long long*>(
                    C + (size_t)(n0 + wn + n * 16 + r15) * 2048 + m0 + wm + m * 16 + g * 4) = v;
            }
    } else {
        float* C = (float*)Cp;
#pragma unroll
        for (int m = 0; m < 4; m++)
#pragma unroll
            for (int n = 0; n < 2; n++)
#pragma unroll
                for (int i = 0; i < 4; i++)
                    C[(size_t)(m0 + wm + m * 16 + g * 4 + i) * 1024 + n0 + wn + n * 16 + r15] =
                        acc[m][n][i];
    }
}

__global__ __launch_bounds__(256)
void gemm_qkv_bf16(const unsigned short* __restrict__ xb, const unsigned short* __restrict__ wqb,
                   const unsigned short* __restrict__ wkb, const unsigned short* __restrict__ wvb,
                   unsigned short* __restrict__ Qb, unsigned short* __restrict__ Kb,
                   unsigned short* __restrict__ Vtb)
{
    int z = blockIdx.z;
    const unsigned short* W = (z == 0) ? wqb : (z == 1) ? wkb : wvb;
    void* C = (z == 0) ? (void*)Qb : (z == 1) ? (void*)Kb : (void*)Vtb;
    gemm_bf16_body(xb, W, C, (z == 2) ? 1 : (z == 0 ? 3 : 0));
}

__global__ __launch_bounds__(256)
void gemm_out_bf16(const unsigned short* __restrict__ Nb, const unsigned short* __restrict__ wob,
                   float* __restrict__ out)
{
    gemm_bf16_body(Nb, wob, out, 2);
}

// ---------------------------------------------------------------------------
// Differential attention v3.
// QB=32 (2 waves, 128 thr), KB=64, grid 1024 = 64 q-blocks x 16 heads.
// Wave-uniform deferred max (threshold 8 in log2 domain): no per-tile shfl.
// Lane-local l partials, reduced once in epilogue. exp2 softmax (Q prescaled
// by 32^-0.5*log2e in GEMM). Mask only on the final (diagonal) tile.
// ---------------------------------------------------------------------------
__global__ __launch_bounds__(128)
void attn_mfma2(const unsigned short* __restrict__ Qb, const unsigned short* __restrict__ Kb,
                const unsigned short* __restrict__ Vtb, unsigned short* __restrict__ Nb,
                const float* __restrict__ lq1, const float* __restrict__ lk1,
                const float* __restrict__ lq2, const float* __restrict__ lk2,
                const float* __restrict__ gamma)
{
    __shared__ char Kl[64 * 128];      // [key][hd 0..63] bf16, swizzled
    __shared__ char Vl[64 * 128];      // [dim][key 0..63] bf16, swizzled
    __shared__ char Pl[2][32 * 128];   // [sub][q-row 0..31][key] bf16, swizzled

    const int tid = threadIdx.x, lane = tid & 63, w = tid >> 6;
    const int g = lane >> 4, r15 = lane & 15;
    const int u = blockIdx.x >> 4, h = blockIdx.x & 15;
    const int qb = (u < 32) ? u : 95 - u;   // causal load-balance pairing
    const int q0 = qb * 32;
    const int row_g = q0 + w * 16 + r15;    // this lane's q-row
    const int prow  = w * 16 + r15;

    float s1 = 0.f, s2 = 0.f;
#pragma unroll
    for (int i = 0; i < 32; i++) { s1 += lq1[i] * lk1[i]; s2 += lq2[i] * lk2[i]; }
    const float LI = 0.4707130183435841f;          // 0.8 - 0.6*exp(-0.6)
    const float lam = expf(s1) - expf(s2) + LI;

    // Q (pre-scaled by 32^-0.5*log2e) as score-MFMA B-operand, loaded once.
    bf16x8 qf0 = *reinterpret_cast<const bf16x8*>(Qb + (size_t)row_g * 1024 + h * 64 + g * 8);
    bf16x8 qf1 = *reinterpret_cast<const bf16x8*>(Qb + (size_t)row_g * 1024 + h * 64 + 32 + g * 8);

    f32x4 oacc[2][4] = {};
    float m_u[2] = {-INFINITY, -INFINITY};   // wave-uniform running max (log2 dom)
    float l_l[2] = {0.f, 0.f};               // lane-local denominator partials

    const int nkb = (qb + 2) >> 1;
    for (int kb = 0; kb < nkb; kb++) {
        const int j0 = kb * 64;
        __syncthreads();
#pragma unroll
        for (int p = 0; p < 4; p++) {
            int idx = p * 128 + tid;
            int row = idx >> 3, c8 = idx & 7;
            bf16x8 v = *reinterpret_cast<const bf16x8*>(Kb + (size_t)(j0 + row) * 1024 + h * 64 + c8 * 8);
            int byte = (row * 128 + c8 * 16) ^ ((row & 7) << 4);
            *reinterpret_cast<bf16x8*>(Kl + byte) = v;
        }
#pragma unroll
        for (int p = 0; p < 4; p++) {
            int idx = p * 128 + tid;
            int row = idx >> 3, c8 = idx & 7;
            bf16x8 v = *reinterpret_cast<const bf16x8*>(Vtb + (size_t)(h * 64 + row) * 2048 + j0 + c8 * 8);
            int byte = (row * 128 + c8 * 16) ^ ((row & 7) << 4);
            *reinterpret_cast<bf16x8*>(Vl + byte) = v;
        }
        __syncthreads();

        // scores: T = K . Q^T  (keys = M-frags, q-rows = N); already log2-scaled
        f32x4 sc0[4] = {}, sc1[4] = {};
#pragma unroll
        for (int m = 0; m < 4; m++) {
            int row = m * 16 + r15;
            int b0 = (row * 128 + g * 16) ^ ((row & 7) << 4);
            int b1 = (row * 128 + g * 16 + 64) ^ ((row & 7) << 4);
            bf16x8 a0 = *reinterpret_cast<const bf16x8*>(Kl + b0);
            bf16x8 a1 = *reinterpret_cast<const bf16x8*>(Kl + b1);
            sc0[m] = MFMA16(a0, qf0, sc0[m]);
            sc1[m] = MFMA16(a1, qf1, sc1[m]);
        }

        const bool diag = (kb == nkb - 1);    // only the last tile crosses the diagonal
#pragma unroll
        for (int s = 0; s < 2; s++) {
            f32x4* sc = s ? sc1 : sc0;
            float sv[4][4];
            float mxl = -INFINITY;
            if (diag) {
#pragma unroll
                for (int m = 0; m < 4; m++)
#pragma unroll
                    for (int i = 0; i < 4; i++) {
                        float xv = ((j0 + m * 16 + g * 4 + i) <= row_g) ? sc[m][i] : -INFINITY;
                        sv[m][i] = xv;
                        mxl = fmaxf(mxl, xv);
                    }
            } else {
#pragma unroll
                for (int m = 0; m < 4; m++)
#pragma unroll
                    for (int i = 0; i < 4; i++) {
                        sv[m][i] = sc[m][i];
                        mxl = fmaxf(mxl, sc[m][i]);
                    }
            }
            // deferred-max: rescale only when headroom (2^8) would be exceeded
            if (__any(mxl > m_u[s] + 8.0f)) {
                float wm = mxl;
                wm = fmaxf(wm, __shfl_xor(wm, 1));
                wm = fmaxf(wm, __shfl_xor(wm, 2));
                wm = fmaxf(wm, __shfl_xor(wm, 4));
                wm = fmaxf(wm, __shfl_xor(wm, 8));
                wm = fmaxf(wm, __shfl_xor(wm, 16));
                wm = fmaxf(wm, __shfl_xor(wm, 32));
                const float corr = exp2f(m_u[s] - wm);   // 0 on first tile
                m_u[s] = wm;
                l_l[s] *= corr;
#pragma unroll
                for (int n = 0; n < 4; n++)
#pragma unroll
                    for (int i = 0; i < 4; i++) oacc[s][n][i] *= corr;
            }
            float sum = 0.f;
#pragma unroll
            for (int m = 0; m < 4; m++) {
                float p0 = exp2f(sv[m][0] - m_u[s]);
                float p1 = exp2f(sv[m][1] - m_u[s]);
                float p2 = exp2f(sv[m][2] - m_u[s]);
                float p3 = exp2f(sv[m][3] - m_u[s]);
                sum += (p0 + p1) + (p2 + p3);
                unsigned long long pv = (unsigned long long)pack2(p0, p1)
                                      | ((unsigned long long)pack2(p2, p3) << 32);
                int byte = (prow * 128 + m * 32 + g * 8) ^ ((prow & 7) << 4);
                *reinterpret_cast<unsigned long long*>(Pl[s] + byte) = pv;
            }
            l_l[s] += sum;
        }

        // PV: O += P . V   (wave-local Pl as A-frags; Vl rows as B-frags)
#pragma unroll
        for (int c = 0; c < 2; c++) {
            int pb = (prow * 128 + g * 16 + c * 64) ^ ((prow & 7) << 4);
            bf16x8 p0 = *reinterpret_cast<const bf16x8*>(Pl[0] + pb);
            bf16x8 p1 = *reinterpret_cast<const bf16x8*>(Pl[1] + pb);
#pragma unroll
            for (int n = 0; n < 4; n++) {
                int vrow = n * 16 + r15;
                int vb = (vrow * 128 + g * 16 + c * 64) ^ ((vrow & 7) << 4);
                bf16x8 vf = *reinterpret_cast<const bf16x8*>(Vl + vb);
                oacc[0][n] = MFMA16(p0, vf, oacc[0][n]);
                oacc[1][n] = MFMA16(p1, vf, oacc[1][n]);
            }
        }
    }

    // epilogue: reduce lane-local l across the 4 key-groups (row total)
    float l0 = l_l[0];
    l0 += __shfl_xor(l0, 16); l0 += __shfl_xor(l0, 32);
    float l1 = l_l[1];
    l1 += __shfl_xor(l1, 16); l1 += __shfl_xor(l1, 32);
    const float r1 = 1.f / l0;
    const float r2 = lam / l1;
    float i1[4], i2[4];
#pragma unroll
    for (int i = 0; i < 4; i++) {
        i1[i] = __shfl(r1, g * 4 + i);
        i2[i] = __shfl(r2, g * 4 + i);
    }
    float o[4][4], ss[4] = {0.f, 0.f, 0.f, 0.f};
#pragma unroll
    for (int n = 0; n < 4; n++)
#pragma unroll
        for (int i = 0; i < 4; i++) {
            float v = oacc[0][n][i] * i1[i] - oacc[1][n][i] * i2[i];
            o[n][i] = v;
            ss[i] = fmaf(v, v, ss[i]);
        }
#pragma unroll
    for (int i = 0; i < 4; i++) {
        ss[i] += __shfl_xor(ss[i], 1);
        ss[i] += __shfl_xor(ss[i], 2);
        ss[i] += __shfl_xor(ss[i], 4);
        ss[i] += __shfl_xor(ss[i], 8);
    }
    const float post = 1.f - LI;
    float gm4[4];
#pragma unroll
    for (int n = 0; n < 4; n++) gm4[n] = gamma[n * 16 + r15];
#pragma unroll
    for (int i = 0; i < 4; i++) {
        const float rs = rsqrtf(ss[i] * 0.015625f + 1e-5f);
#pragma unroll
        for (int n = 0; n < 4; n++) {
            Nb[(size_t)(q0 + w * 16 + g * 4 + i) * 1024 + h * 64 + n * 16 + r15] =
                f2bf(o[n][i] * rs * gm4[n] * post);
        }
    }
}

// ---------------------------------------------------------------------------
extern "C" void kernel_launch(void* const* d_in, const int* in_sizes, int n_in,
                              void* d_out, int out_size, void* d_ws, size_t ws_size,
                              hipStream_t stream)
{
    const float* x   = (const float*)d_in[0];
    const float* Wq  = (const float*)d_in[1];
    const float* Wk  = (const float*)d_in[2];
    const float* Wv  = (const float*)d_in[3];
    const float* Wo  = (const float*)d_in[4];
    const float* lq1 = (const float*)d_in[5];
    const float* lk1 = (const float*)d_in[6];
    const float* lq2 = (const float*)d_in[7];
    const float* lk2 = (const float*)d_in[8];
    const float* gm  = (const float*)d_in[9];
    float* out = (float*)d_out;

    unsigned short* ws  = (unsigned short*)d_ws;
    unsigned short* xb  = ws;               // 2M elts
    unsigned short* wqb = xb  + 2097152;    // 1M
    unsigned short* wkb = wqb + 1048576;    // 1M
    unsigned short* wvb = wkb + 1048576;    // 1M
    unsigned short* wob = wvb + 1048576;    // 1M
    unsigned short* Qb  = wob + 1048576;    // 2M
    unsigned short* Kb  = Qb  + 2097152;    // 2M
    unsigned short* Vtb = Kb  + 2097152;    // 2M [1024 dims][2048 seq]
    unsigned short* Nb  = Vtb + 2097152;    // 2M

    convert_bf16<<<6144, 256, 0, stream>>>(x, Wq, Wk, Wv, Wo, xb, wqb, wkb, wvb, wob);
    gemm_qkv_bf16<<<dim3(16, 16, 3), 256, 0, stream>>>(xb, wqb, wkb, wvb, Qb, Kb, Vtb);
    attn_mfma2<<<1024, 128, 0, stream>>>(Qb, Kb, Vtb, Nb, lq1, lk1, lq2, lk2, gm);
    gemm_out_bf16<<<dim3(16, 16), 256, 0, stream>>>(Nb, wob, out);
}